// Round 7
// baseline (183.767 us; speedup 1.0000x reference)
//
#include <hip/hip_runtime.h>

// MoE top-2 of 3x3 SAME convs via bf16 MFMA implicit GEMM.
//
// R7: main was latency-exposed, not bandwidth-bound (all pipes <22%,
// occupancy 16% ~ 5 waves/CU, grid 3.5 blocks/CU, 6 barriers/block).
// Restructure: co-split blocks (32 co x 64 px x 4 rows, grid 1792 = 7/CU),
// acc 128->64 VGPRs, A staged once per ks-half for ALL 9 taps (36.9 KB LDS,
// 4 barriers/block), __launch_bounds__(256,4) -> target 16 waves/CU.
// Prep (xpose+wpack fused) unchanged from R6.

#define BB 64
#define CC 64
#define COO 64
#define HH 56
#define WW 56

typedef __bf16 bf16x8 __attribute__((ext_vector_type(8)));
typedef float  f32x4  __attribute__((ext_vector_type(4)));

// ---- prep: fused transpose (fat blocks) + weight pack ----------------------
__global__ __launch_bounds__(256) void prep_kernel(
    const float* __restrict__ x, const float* __restrict__ Wexp,
    __bf16* __restrict__ xT, __bf16* __restrict__ Wpack)
{
    const int bx  = blockIdx.x;
    const int tid = threadIdx.x;

    if (bx < 960) {
        // ---- xpose part: 4 hp-rows per block -------------------------------
        __shared__ float tile[CC][WW + 1];   // stride 57: reads 2-way max
        const int b   = bx / 15;
        const int grp = bx - b * 15;         // 0..14 -> hp = grp*4 + rr
        #pragma unroll 1
        for (int rr = 0; rr < 4; ++rr) {
            const int hp = grp * 4 + rr;
            if (hp >= 58) break;
            __bf16* dst = xT + ((size_t)b * 58 + hp) * 66 * CC;
            const bool interior = (hp >= 1 && hp <= HH);
            if (!interior) {                 // pad row: zero-fill (no LDS use)
                bf16x8 z = {};
                for (int j = tid; j < 66 * CC / 8; j += 256)
                    *(bf16x8*)(dst + j * 8) = z;
                continue;                    // hp uniform per block: no diverge
            }
            const int h = hp - 1;
            const float* xb = x + (size_t)b * CC * HH * WW + (size_t)h * WW;
            for (int i = tid; i < CC * 14; i += 256) {
                const int c = i / 14, wq = i - c * 14;
                const float4 f = *(const float4*)(xb + (size_t)c * HH * WW + wq * 4);
                tile[c][wq * 4 + 0] = f.x; tile[c][wq * 4 + 1] = f.y;
                tile[c][wq * 4 + 2] = f.z; tile[c][wq * 4 + 3] = f.w;
            }
            __syncthreads();
            for (int j = tid; j < 66 * 8; j += 256) {
                const int wc = j >> 3, cg = j & 7;
                bf16x8 v = {};
                if (wc >= 1 && wc <= WW) {
                    const int w = wc - 1;
                    #pragma unroll
                    for (int u = 0; u < 8; ++u)
                        v[u] = (__bf16)tile[cg * 8 + u][w];
                }
                *(bf16x8*)(dst + wc * CC + cg * 8) = v;   // 16B coalesced
            }
            __syncthreads();                 // before next rr reuses tile
        }
    } else {
        // ---- wpack part (verified) -----------------------------------------
        // Wpack[e*36864 + rs*4096 + ks*2048 + mt*512 + lane*8 + j]
        //   = bf16( Wexp[e][mt*16+(lane&15)][ks*32+(lane>>4)*8+j][r][s] )
        const int wp = bx - 960;             // 0..71
        const int e  = wp / 9, rs = wp - e * 9;
        const int r  = rs / 3, s  = rs - r * 3;
        for (int idx = tid; idx < 4096; idx += 256) {
            const int ks   = idx >> 11;
            const int rem  = idx & 2047;
            const int mt   = rem >> 9;
            const int lane = (rem >> 3) & 63;
            const int j    = idx & 7;
            const int co = mt * 16 + (lane & 15);
            const int c  = ks * 32 + ((lane >> 4) << 3) + j;
            const float v = Wexp[((((size_t)e * COO + co) * CC + c) * 3 + r) * 3 + s];
            Wpack[(size_t)e * 36864 + (size_t)rs * 4096 + idx] = (__bf16)v;
        }
    }
}

// ---- Main: MFMA implicit GEMM, 32co x 64px x 4rows per block ---------------
__global__ __launch_bounds__(256, 4) void moe_conv_mfma(
    const __bf16* __restrict__ xT, const __bf16* __restrict__ Wpack,
    const float* __restrict__ gate_w, const int* __restrict__ gate_i,
    const float* __restrict__ bexp, float* __restrict__ out)
{
    // ldsA[q=slot*18+tap*2+mtl][lane][j] : 36 chunks x 1 KB = 36,864 B
    __shared__ __bf16 ldsA[18432];

    const int bx  = blockIdx.x;         // 0..27 : hg*2 + coh
    const int b   = blockIdx.y;
    const int hg  = bx >> 1, coh = bx & 1;
    const int h0  = hg * 4;             // rows h0..h0+3
    const int tid = threadIdx.x;
    const int wid = tid >> 6, lane = tid & 63;
    const int n15 = lane & 15, quad = lane >> 4;
    const int wcol = wid * 16 + n15;    // padded col 0..63

    const int   e0 = gate_i[b * 2 + 0], e1 = gate_i[b * 2 + 1];
    const float g0 = gate_w[b * 2 + 0], g1 = gate_w[b * 2 + 1];

    const __bf16* s0p = Wpack + (size_t)e0 * 36864;
    const __bf16* s1p = Wpack + (size_t)e1 * 36864;
    const __bf16* xb  = xT + (size_t)b * 58 * 66 * CC;

    f32x4 acc[2][2][4] = {};            // [slot][mtl][row t]

    #pragma unroll 1
    for (int ks = 0; ks < 2; ++ks) {
        __syncthreads();                // prior ks readers done / entry
        // stage A: 36 chunks of 1 KB (this ks, all taps, both slots, 2 mtl)
        #pragma unroll
        for (int i = 0; i < 9; ++i) {
            const int q    = wid * 9 + i;           // 0..35
            const int slot = q / 18;
            const int rem  = q - slot * 18;
            const int tap  = rem >> 1, mtl = rem & 1;
            const __bf16* src = (slot ? s1p : s0p)
                + (size_t)tap * 4096 + ks * 2048 + (coh * 2 + mtl) * 512 + lane * 8;
            *(uint4*)&ldsA[q * 512 + lane * 8] = *(const uint4*)src;
        }
        __syncthreads();

        #pragma unroll 1
        for (int tap = 0; tap < 9; ++tap) {
            const int r = tap / 3, s = tap - r * 3;
            bf16x8 bfr[4];
            #pragma unroll
            for (int t = 0; t < 4; ++t) {
                const int hr1 = h0 + t + r;          // padded row 0..57
                const int wc1 = wcol + s;            // padded col 0..65
                bfr[t] = *(const bf16x8*)(
                    xb + (size_t)(hr1 * 66 + wc1) * CC + ks * 32 + quad * 8);
            }
            #pragma unroll
            for (int slot = 0; slot < 2; ++slot) {
                #pragma unroll
                for (int mtl = 0; mtl < 2; ++mtl) {
                    const bf16x8 af = *(const bf16x8*)
                        &ldsA[(size_t)((slot * 18 + tap * 2 + mtl) * 512 + lane * 8)];
                    #pragma unroll
                    for (int t = 0; t < 4; ++t)
                        acc[slot][mtl][t] = __builtin_amdgcn_mfma_f32_16x16x32_bf16(
                            af, bfr[t], acc[slot][mtl][t], 0, 0, 0);
                }
            }
        }
    }

    // Epilogue: D layout col=lane&15 (pixel), row=quad*4+reg (co within tile)
    if (wcol < WW) {
        #pragma unroll
        for (int t = 0; t < 4; ++t) {
            const int h = h0 + t;
            #pragma unroll
            for (int mtl = 0; mtl < 2; ++mtl) {
                #pragma unroll
                for (int v = 0; v < 4; ++v) {
                    const int co = coh * 32 + mtl * 16 + quad * 4 + v;
                    float a0 = acc[0][mtl][t][v] + bexp[e0 * COO + co];
                    float a1 = acc[1][mtl][t][v] + bexp[e1 * COO + co];
                    a0 = fmaxf(a0, 0.f);
                    a1 = fmaxf(a1, 0.f);
                    out[(((size_t)b * COO + co) * HH + h) * WW + wcol] =
                        g0 * a0 + g1 * a1;
                }
            }
        }
    }
}

extern "C" void kernel_launch(void* const* d_in, const int* in_sizes, int n_in,
                              void* d_out, int out_size, void* d_ws, size_t ws_size,
                              hipStream_t stream) {
    const float* x      = (const float*)d_in[0];
    const float* gate_w = (const float*)d_in[1];
    const int*   gate_i = (const int*)  d_in[2];
    const float* Wexp   = (const float*)d_in[3];
    const float* bexp   = (const float*)d_in[4];
    float* out = (float*)d_out;

    // Wpack first (fixed 589,824 B, 16B-aligned), then xT (31,358,976 B).
    __bf16* Wpack = (__bf16*)d_ws;
    __bf16* xT    = (__bf16*)((char*)d_ws + 589824);

    prep_kernel<<<dim3(1032), 256, 0, stream>>>(x, Wexp, xT, Wpack);
    moe_conv_mfma<<<dim3(28, BB), 256, 0, stream>>>(xT, Wpack, gate_w, gate_i,
                                                    bexp, out);
}